// Round 1
// baseline (4375.541 us; speedup 1.0000x reference)
//
#include <hip/hip_runtime.h>
#include <hip/hip_bf16.h>
#include <math.h>

// Exact fp32 brute-force KNN (K=32) with inverse-squared-distance weighting.
// points:[16384,64] features:[20000,64] targets:[20000] -> out:[16384]
//
// Structure: block = 256 thr = 4 waves; each wave owns WQ=8 queries.
// Queries staged in LDS (uniform/broadcast reads). Each lane owns one feature
// row per 64-feature chunk; computes 8 dot products; per-query sorted top-32
// kept in LDS, wave-parallel shift-insertion guarded by ballot.

#define NQ   16384
#define MM   20000
#define DD   64
#define KK   32
#define BQ   32      // queries per block
#define WQ   8       // queries per wave
#define NCH  ((MM + 63) / 64)

__global__ __launch_bounds__(256) void hp_knn_kernel(
    const float* __restrict__ points,
    const float* __restrict__ features,
    const float* __restrict__ targets,
    float* __restrict__ out)
{
    __shared__ __align__(16) float Qs[BQ][DD];
    __shared__ float qn_s[BQ];
    __shared__ float top_d[BQ][KK];   // sorted ascending per query
    __shared__ int   top_i[BQ][KK];

    const int tid  = threadIdx.x;
    const int lane = tid & 63;
    const int wv   = tid >> 6;
    const int qb   = wv * WQ;

    // ---- stage this block's 32 query rows into LDS (2 float4 per thread) ----
    {
        const float4* src = (const float4*)(points + (size_t)blockIdx.x * BQ * DD);
        float4* dst = (float4*)&Qs[0][0];
        #pragma unroll
        for (int i = 0; i < (BQ * DD / 4) / 256; ++i)
            dst[tid + i * 256] = src[tid + i * 256];
    }
    // ---- init top-k ----
    {
        float* td = &top_d[0][0];
        int*   ti = &top_i[0][0];
        for (int i = tid; i < BQ * KK; i += 256) { td[i] = __builtin_inff(); ti[i] = 0; }
    }
    __syncthreads();
    // ---- query norms ----
    if (tid < BQ) {
        float s = 0.f;
        #pragma unroll
        for (int d = 0; d < DD; ++d) s = fmaf(Qs[tid][d], Qs[tid][d], s);
        qn_s[tid] = s;
    }
    __syncthreads();

    // ---- main scan over features, 64 per chunk (one row per lane) ----
    for (int c = 0; c < NCH; ++c) {
        const int m  = c * 64 + lane;
        const int mc = (m < MM) ? m : (MM - 1);

        float f[DD];
        {
            const float4* frow = (const float4*)(features + (size_t)mc * DD);
            #pragma unroll
            for (int b = 0; b < DD / 4; ++b) {
                float4 v = frow[b];
                f[4*b+0] = v.x; f[4*b+1] = v.y; f[4*b+2] = v.z; f[4*b+3] = v.w;
            }
        }
        float fn = 0.f;
        #pragma unroll
        for (int d = 0; d < DD; ++d) fn = fmaf(f[d], f[d], fn);

        float d2v[WQ];
        #pragma unroll
        for (int qi = 0; qi < WQ; ++qi) {
            const float4* qrow = (const float4*)&Qs[qb + qi][0];
            float a0 = 0.f, a1 = 0.f, a2 = 0.f, a3 = 0.f;
            #pragma unroll
            for (int b = 0; b < DD / 4; ++b) {
                float4 q4 = qrow[b];
                a0 = fmaf(q4.x, f[4*b+0], a0);
                a1 = fmaf(q4.y, f[4*b+1], a1);
                a2 = fmaf(q4.z, f[4*b+2], a2);
                a3 = fmaf(q4.w, f[4*b+3], a3);
            }
            const float dot = (a0 + a1) + (a2 + a3);
            float d2 = fmaxf(qn_s[qb + qi] + fn - 2.f * dot, 0.f);
            d2v[qi] = (m < MM) ? d2 : __builtin_inff();
        }

        // ---- wave-collaborative sorted insert per query ----
        #pragma unroll
        for (int qi = 0; qi < WQ; ++qi) {
            const int q = qb + qi;
            const float kth = top_d[q][KK - 1];           // uniform broadcast read
            unsigned long long ball = __ballot(d2v[qi] < kth);
            while (ball) {
                const int j = __builtin_ctzll(ball);
                ball &= ball - 1;
                const float dval = __shfl(d2v[qi], j);
                const int   mval = c * 64 + j;
                if (lane < KK) {
                    const float cur = top_d[q][lane];
                    if (cur > dval) {                     // lanes >= insert pos shift right
                        const float prevd = (lane > 0) ? top_d[q][lane - 1] : -1.f;
                        const int   previ = (lane > 0) ? top_i[q][lane - 1] : 0;
                        const bool  tp = (prevd > dval);
                        top_d[q][lane] = tp ? prevd : dval;
                        top_i[q][lane] = tp ? previ : mval;
                    }
                }
            }
        }
    }

    // ---- epilogue: weights, gather targets, reduce, write ----
    #pragma unroll
    for (int qi = 0; qi < WQ; ++qi) {
        const int q = qb + qi;
        float w = 0.f, wt = 0.f;
        if (lane < KK) {
            const float dd = top_d[q][lane];
            const float ww = 1.f / (dd + 1e-4f);
            w  = ww;
            wt = ww * targets[top_i[q][lane]];
        }
        #pragma unroll
        for (int off = 32; off >= 1; off >>= 1) {
            w  += __shfl_xor(w, off);
            wt += __shfl_xor(wt, off);
        }
        if (lane == 0)
            out[(size_t)blockIdx.x * BQ + q] = wt / fmaxf(w, 1e-9f);
    }
}

extern "C" void kernel_launch(void* const* d_in, const int* in_sizes, int n_in,
                              void* d_out, int out_size, void* d_ws, size_t ws_size,
                              hipStream_t stream) {
    const float* points   = (const float*)d_in[0];
    const float* features = (const float*)d_in[1];
    const float* targets  = (const float*)d_in[2];
    float* out = (float*)d_out;
    hp_knn_kernel<<<dim3(NQ / BQ), dim3(256), 0, stream>>>(points, features, targets, out);
}

// Round 2
// 1109.200 us; speedup vs baseline: 3.9448x; 3.9448x over previous
//
#include <hip/hip_runtime.h>
#include <hip/hip_bf16.h>
#include <math.h>

// Split-bf16 MFMA exact-KNN (K=32) + inverse-squared-distance weighting.
// points:[16384,64] features:[20000,64] targets:[20000] -> out:[16384]
//
// d2 = qn + fn - 2*dot; dot via 4-term split-bf16 MFMA (hh+hl+lh+ll) ->
// ~1e-6 abs error, selection-safe. Selection on s = fn - 2*dot (qn const/query).

#define NQ   16384
#define MM   20000
#define DD   64
#define KK   32
#define MPAD 20032
#define NCH  (MPAD / 64)   // 313

typedef __attribute__((ext_vector_type(8))) short bf16x8;
typedef __attribute__((ext_vector_type(4))) float f32x4;

// ---- workspace layout (bytes) ----
#define OFF_FH 0
#define SZ_FP  (MPAD * DD * 2)              // one bf16 feature plane
#define OFF_FL (OFF_FH + SZ_FP)
#define OFF_FN (OFF_FL + SZ_FP)
#define SZ_FN  (MPAD * 4)
#define OFF_QH (OFF_FN + SZ_FN)
#define SZ_QP  (NQ * DD * 2)
#define OFF_QL (OFF_QH + SZ_QP)
#define OFF_QN (OFF_QL + SZ_QP)
#define SZ_QN  (NQ * 4)
#define WS_REQ (OFF_QN + SZ_QN)             // ~9.47 MB

__device__ __forceinline__ unsigned int bf16_rne(float x) {
    unsigned int xb = __float_as_uint(x);
    return (xb + 0x7fffu + ((xb >> 16) & 1u)) & 0xffff0000u;
}

// one wave = one 64-dim row; split into hi/lo bf16 planes + fp32 norm
__global__ void prep_split(const float* __restrict__ src,
                           unsigned short* __restrict__ ph,
                           unsigned short* __restrict__ pl,
                           float* __restrict__ nrm, int nrows_real) {
    const int e = blockIdx.x * 256 + threadIdx.x;
    const int m = e >> 6;
    const int lane = threadIdx.x & 63;
    const bool real = (m < nrows_real);
    float x = real ? src[e] : 0.f;
    unsigned int hb = bf16_rne(x);
    float xh = __uint_as_float(hb);
    unsigned int lb = bf16_rne(x - xh);
    ph[e] = (unsigned short)(hb >> 16);
    pl[e] = (unsigned short)(lb >> 16);
    float s = x * x;
    #pragma unroll
    for (int o = 32; o >= 1; o >>= 1) s += __shfl_xor(s, o);
    if (lane == 0) nrm[m] = real ? s : __builtin_inff();
}

__global__ __launch_bounds__(512) void knn_mfma(
    const unsigned short* __restrict__ Fh, const unsigned short* __restrict__ Fl,
    const float* __restrict__ fn,
    const unsigned short* __restrict__ Qh, const unsigned short* __restrict__ Ql,
    const float* __restrict__ qn,
    const float* __restrict__ targets, float* __restrict__ out)
{
    __shared__ float top_d[8][16][33];
    __shared__ int   top_i[8][16][33];

    const int tid  = threadIdx.x;
    const int lane = tid & 63;
    const int w    = tid >> 6;      // 0..7
    const int qg   = w & 3;         // query group
    const int half = w >> 2;        // m-half (chunk parity)
    const int qbase = blockIdx.x * 64 + qg * 16;

    for (int i = tid; i < 8 * 16 * 33; i += 512) {
        (&top_d[0][0][0])[i] = __builtin_inff();
        (&top_i[0][0][0])[i] = 0;
    }
    __syncthreads();

    // B-operand (Q^T) fragments, stationary: lane holds Q[qbase+(lane&15)][kof..kof+8)
    const int qrow = qbase + (lane & 15);
    const int kof  = (lane >> 4) * 8;
    const bf16x8 qh0 = *(const bf16x8*)(Qh + (size_t)qrow * DD + kof);
    const bf16x8 qh1 = *(const bf16x8*)(Qh + (size_t)qrow * DD + kof + 32);
    const bf16x8 ql0 = *(const bf16x8*)(Ql + (size_t)qrow * DD + kof);
    const bf16x8 ql1 = *(const bf16x8*)(Ql + (size_t)qrow * DD + kof + 32);

    float* myTd = &top_d[w][0][0];      // [q*33 + slot]
    int*   myTi = &top_i[w][0][0];

    for (int c = half; c < NCH; c += 2) {
        const int mbase = c * 64;

        // A-operand (F rows) fragments for 4 subtiles + fn vectors — issue all loads first
        bf16x8 Ah0[4], Ah1[4], Al0[4], Al1[4];
        f32x4  fnv[4];
        #pragma unroll
        for (int t = 0; t < 4; ++t) {
            const int frow = mbase + t * 16 + (lane & 15);
            const unsigned short* ph = Fh + (size_t)frow * DD + kof;
            const unsigned short* pl = Fl + (size_t)frow * DD + kof;
            Ah0[t] = *(const bf16x8*)(ph);
            Ah1[t] = *(const bf16x8*)(ph + 32);
            Al0[t] = *(const bf16x8*)(pl);
            Al1[t] = *(const bf16x8*)(pl + 32);
            fnv[t] = *(const f32x4*)(fn + mbase + t * 16 + (lane >> 4) * 4);
        }

        #pragma unroll
        for (int t = 0; t < 4; ++t) {
            f32x4 acc = {0.f, 0.f, 0.f, 0.f};
            acc = __builtin_amdgcn_mfma_f32_16x16x32_bf16(Ah0[t], qh0, acc, 0, 0, 0);
            acc = __builtin_amdgcn_mfma_f32_16x16x32_bf16(Ah1[t], qh1, acc, 0, 0, 0);
            acc = __builtin_amdgcn_mfma_f32_16x16x32_bf16(Ah0[t], ql0, acc, 0, 0, 0);
            acc = __builtin_amdgcn_mfma_f32_16x16x32_bf16(Ah1[t], ql1, acc, 0, 0, 0);
            acc = __builtin_amdgcn_mfma_f32_16x16x32_bf16(Al0[t], qh0, acc, 0, 0, 0);
            acc = __builtin_amdgcn_mfma_f32_16x16x32_bf16(Al1[t], qh1, acc, 0, 0, 0);
            acc = __builtin_amdgcn_mfma_f32_16x16x32_bf16(Al0[t], ql0, acc, 0, 0, 0);
            acc = __builtin_amdgcn_mfma_f32_16x16x32_bf16(Al1[t], ql1, acc, 0, 0, 0);

            // s = fn - 2*dot for rows (lane>>4)*4+j of this subtile, col q = lane&15
            float s0 = fnv[t][0] - 2.f * acc[0];
            float s1 = fnv[t][1] - 2.f * acc[1];
            float s2 = fnv[t][2] - 2.f * acc[2];
            float s3 = fnv[t][3] - 2.f * acc[3];

            const int q = lane & 15;
            const float kth = myTd[q * 33 + 31];
            const bool pr = (s0 < kth) | (s1 < kth) | (s2 < kth) | (s3 < kth);
            unsigned long long bal = __ballot(pr);
            const int rbase = mbase + t * 16;
            while (bal) {
                const int src = __builtin_ctzll(bal);
                bal &= bal - 1;
                const int qu   = src & 15;
                const int mrow = rbase + (src >> 4) * 4;
                const float b0 = __shfl(s0, src);
                const float b1 = __shfl(s1, src);
                const float b2 = __shfl(s2, src);
                const float b3 = __shfl(s3, src);
                const float bv[4] = {b0, b1, b2, b3};
                #pragma unroll
                for (int jj = 0; jj < 4; ++jj) {
                    const float val = bv[jj];
                    const float kcur = myTd[qu * 33 + 31];   // uniform broadcast
                    if (val < kcur) {                        // wave-uniform branch
                        const int mi = mrow + jj;
                        const float cur_d = myTd[qu * 33 + (lane & 31)];
                        const int   cur_i = myTi[qu * 33 + (lane & 31)];
                        float prev_d = __shfl_up(cur_d, 1);
                        int   prev_i = __shfl_up(cur_i, 1);
                        if (lane == 0) prev_d = -__builtin_inff();
                        if (lane < 32 && cur_d > val) {
                            const bool tp = (prev_d > val);
                            myTd[qu * 33 + lane] = tp ? prev_d : val;
                            myTi[qu * 33 + lane] = tp ? prev_i : mi;
                        }
                    }
                }
            }
        }
    }

    __syncthreads();

    // ---- epilogue: merge-path the two sorted half-lists, weight, reduce ----
    if (w < 4) {
        const float* Ad = &top_d[w][0][0];     const int* Ai = &top_i[w][0][0];
        const float* Bd = &top_d[w + 4][0][0]; const int* Bi = &top_i[w + 4][0][0];
        for (int q = 0; q < 16; ++q) {
            const int qglob = qbase + q;
            const int s = lane & 31;
            float myd; int myi; int cnt = 0;
            if (lane < 32) {
                myd = Ad[q * 33 + s]; myi = Ai[q * 33 + s];
                #pragma unroll
                for (int st = 32; st >= 1; st >>= 1) {
                    const int t2 = cnt + st;
                    if (t2 <= 32 && Bd[q * 33 + t2 - 1] < myd) cnt = t2;
                }
            } else {
                myd = Bd[q * 33 + s]; myi = Bi[q * 33 + s];
                #pragma unroll
                for (int st = 32; st >= 1; st >>= 1) {
                    const int t2 = cnt + st;
                    if (t2 <= 32 && Ad[q * 33 + t2 - 1] <= myd) cnt = t2;
                }
            }
            const int rank = s + cnt;
            float nume = 0.f, deno = 0.f;
            if (rank < KK) {
                const float d2 = fmaxf(qn[qglob] + myd, 0.f);
                const float wv = 1.f / (d2 + 1e-4f);
                nume = wv * targets[myi];
                deno = wv;
            }
            #pragma unroll
            for (int o = 32; o >= 1; o >>= 1) {
                nume += __shfl_xor(nume, o);
                deno += __shfl_xor(deno, o);
            }
            if (lane == 0) out[qglob] = nume / fmaxf(deno, 1e-9f);
        }
    }
}

// ---------------- fallback: round-1 exact fp32 vector kernel ----------------
#define BQ 32
#define WQ 8
__global__ __launch_bounds__(256) void hp_knn_kernel(
    const float* __restrict__ points, const float* __restrict__ features,
    const float* __restrict__ targets, float* __restrict__ out)
{
    __shared__ __align__(16) float Qs[BQ][DD];
    __shared__ float qn_s[BQ];
    __shared__ float topd[BQ][KK];
    __shared__ int   topi[BQ][KK];
    const int tid = threadIdx.x, lane = tid & 63, wv = tid >> 6, qb = wv * WQ;
    {
        const float4* src = (const float4*)(points + (size_t)blockIdx.x * BQ * DD);
        float4* dst = (float4*)&Qs[0][0];
        #pragma unroll
        for (int i = 0; i < (BQ * DD / 4) / 256; ++i) dst[tid + i * 256] = src[tid + i * 256];
    }
    for (int i = tid; i < BQ * KK; i += 256) { (&topd[0][0])[i] = __builtin_inff(); (&topi[0][0])[i] = 0; }
    __syncthreads();
    if (tid < BQ) {
        float s = 0.f;
        #pragma unroll
        for (int d = 0; d < DD; ++d) s = fmaf(Qs[tid][d], Qs[tid][d], s);
        qn_s[tid] = s;
    }
    __syncthreads();
    for (int c = 0; c < (MM + 63) / 64; ++c) {
        const int m = c * 64 + lane, mc = (m < MM) ? m : (MM - 1);
        float f[DD];
        const float4* fr = (const float4*)(features + (size_t)mc * DD);
        #pragma unroll
        for (int b = 0; b < DD / 4; ++b) { float4 v = fr[b]; f[4*b]=v.x; f[4*b+1]=v.y; f[4*b+2]=v.z; f[4*b+3]=v.w; }
        float fnv = 0.f;
        #pragma unroll
        for (int d = 0; d < DD; ++d) fnv = fmaf(f[d], f[d], fnv);
        float d2v[WQ];
        #pragma unroll
        for (int qi = 0; qi < WQ; ++qi) {
            const float4* qr = (const float4*)&Qs[qb + qi][0];
            float a0=0,a1=0,a2=0,a3=0;
            #pragma unroll
            for (int b = 0; b < DD / 4; ++b) {
                float4 q4 = qr[b];
                a0 = fmaf(q4.x, f[4*b], a0); a1 = fmaf(q4.y, f[4*b+1], a1);
                a2 = fmaf(q4.z, f[4*b+2], a2); a3 = fmaf(q4.w, f[4*b+3], a3);
            }
            float d2 = fmaxf(qn_s[qb+qi] + fnv - 2.f*((a0+a1)+(a2+a3)), 0.f);
            d2v[qi] = (m < MM) ? d2 : __builtin_inff();
        }
        #pragma unroll
        for (int qi = 0; qi < WQ; ++qi) {
            const int q = qb + qi;
            unsigned long long ball = __ballot(d2v[qi] < topd[q][KK-1]);
            while (ball) {
                const int j = __builtin_ctzll(ball); ball &= ball - 1;
                const float dval = __shfl(d2v[qi], j); const int mval = c * 64 + j;
                if (lane < KK) {
                    const float cur = topd[q][lane];
                    if (cur > dval) {
                        const float pd = (lane > 0) ? topd[q][lane-1] : -1.f;
                        const int   pi = (lane > 0) ? topi[q][lane-1] : 0;
                        const bool tp = (pd > dval);
                        topd[q][lane] = tp ? pd : dval; topi[q][lane] = tp ? pi : mval;
                    }
                }
            }
        }
    }
    #pragma unroll
    for (int qi = 0; qi < WQ; ++qi) {
        const int q = qb + qi;
        float wsum = 0.f, wt = 0.f;
        if (lane < KK) {
            const float ww = 1.f / (topd[q][lane] + 1e-4f);
            wsum = ww; wt = ww * targets[topi[q][lane]];
        }
        #pragma unroll
        for (int o = 32; o >= 1; o >>= 1) { wsum += __shfl_xor(wsum, o); wt += __shfl_xor(wt, o); }
        if (lane == 0) out[(size_t)blockIdx.x * BQ + q] = wt / fmaxf(wsum, 1e-9f);
    }
}

extern "C" void kernel_launch(void* const* d_in, const int* in_sizes, int n_in,
                              void* d_out, int out_size, void* d_ws, size_t ws_size,
                              hipStream_t stream) {
    const float* points   = (const float*)d_in[0];
    const float* features = (const float*)d_in[1];
    const float* targets  = (const float*)d_in[2];
    float* out = (float*)d_out;

    if (ws_size < (size_t)WS_REQ) {
        hp_knn_kernel<<<dim3(NQ / BQ), dim3(256), 0, stream>>>(points, features, targets, out);
        return;
    }
    char* ws = (char*)d_ws;
    unsigned short* Fh = (unsigned short*)(ws + OFF_FH);
    unsigned short* Fl = (unsigned short*)(ws + OFF_FL);
    float*          fn = (float*)(ws + OFF_FN);
    unsigned short* Qh = (unsigned short*)(ws + OFF_QH);
    unsigned short* Ql = (unsigned short*)(ws + OFF_QL);
    float*          qnp= (float*)(ws + OFF_QN);

    prep_split<<<dim3(MPAD * DD / 256), dim3(256), 0, stream>>>(features, Fh, Fl, fn, MM);
    prep_split<<<dim3(NQ * DD / 256),  dim3(256), 0, stream>>>(points,   Qh, Ql, qnp, NQ);
    knn_mfma<<<dim3(NQ / 64), dim3(512), 0, stream>>>(Fh, Fl, fn, Qh, Ql, qnp, targets, out);
}